// Round 25
// baseline (164.270 us; speedup 1.0000x reference)
//
#include <hip/hip_runtime.h>
#include <hip/hip_fp16.h>
#include <math.h>

#define N_NODES 32768
#define N_EDGES 262144
#define OUTC 54      // 16 emb + 38 msg
#define TPW  40      // tp row stride in HALVES (38 used, 80 B, 16B-aligned)
#define TGRID 64     // d0 samples per bin (65 points incl. both ends)
#define TENT 384     // floats per table entry: 16 i * 24 padded cols
#define NBINS 1345   // 21*64 in-range bins + 1 out-of-range bin
#define TBLOCKS 1365 // 21*65 table entries
#define CBLK2 (N_EDGES/512)  // count blocks, 2 edges per thread

__device__ __forceinline__ unsigned pkh(float a, float b) {
    auto r = __builtin_amdgcn_cvt_pkrtz(a, b);   // v_cvt_pkrtz_f16_f32
    union { decltype(r) v; unsigned u; } cv;
    cv.v = r;
    return cv.u;
}

// ---------------- Kernel 1: node embeddings + cursor zeroing --------------
__global__ __launch_bounds__(256) void node_emb_kernel(
    const float* __restrict__ x, const float* __restrict__ W1,
    const float* __restrict__ W2, float* __restrict__ out,
    float* __restrict__ znode,
    int* __restrict__ cursor_dst, int* __restrict__ cursor_bin)
{
    int n = blockIdx.x * blockDim.x + threadIdx.x;
    if (n >= N_NODES) return;
    cursor_dst[n] = 0;
    cursor_bin[n] = 0;

    const float inv10 = 0.31622776601683794f;
    const float inv64 = 0.125f;

    float xr[10];
    #pragma unroll
    for (int i = 0; i < 10; ++i) xr[i] = x[n*10 + i];

    float t[64];
    #pragma unroll
    for (int k = 0; k < 64; ++k) {
        float acc = 0.f;
        #pragma unroll
        for (int i = 0; i < 10; ++i) acc = fmaf(xr[i], W1[i*64 + k], acc);
        t[k] = acc * inv10;
    }

    float e[16];
    #pragma unroll
    for (int j = 0; j < 16; ++j) e[j] = 0.f;
    #pragma unroll
    for (int k = 0; k < 64; ++k) {
        float tk = t[k];
        #pragma unroll
        for (int j = 0; j < 16; ++j) e[j] = fmaf(tk, W2[k*16 + j], e[j]);
    }
    float4* zb = (float4*)(znode + (size_t)n * 16);
    #pragma unroll
    for (int q = 0; q < 4; ++q) {
        float4 v = make_float4(e[q*4+0]*inv64, e[q*4+1]*inv64,
                               e[q*4+2]*inv64, e[q*4+3]*inv64);
        zb[q] = v;
        out[n*OUTC + q*4 + 0] = v.x;
        out[n*OUTC + q*4 + 1] = v.y;
        out[n*OUTC + q*4 + 2] = v.z;
        out[n*OUTC + q*4 + 3] = v.w;
    }
}

// ---------------- prep: fused table-build + count/geometry ----------------
__global__ __launch_bounds__(256) void prep_kernel(
    const float* __restrict__ Wt1, const float* __restrict__ Wt2,
    float* __restrict__ T,
    const int* __restrict__ ei, const float* __restrict__ pos,
    int* __restrict__ cd, int* __restrict__ cb, int* __restrict__ ebin,
    float4* __restrict__ evec)
{
    __shared__ int hist[NBINS];
    __shared__ float h[64];
    int t = threadIdx.x;

    if (blockIdx.x < TBLOCKS) {
        // ---- table part ----
        int entry = blockIdx.x;            // 0 .. 21*65-1
        int m = entry / 65;
        int g = entry - m * 65;
        float d0 = (float)g * (1.0f / TGRID);
        float d1 = d0 - 1.0f;
        int j0 = m - 1, j1 = m;
        const float sq20 = 4.47213595499958f;

        float f0 = 0.f, f1 = 0.f;
        if (j0 >= 0 && j0 < 20)
            f0 = 1.14136f * expf(2.0f - 1.0f/(1.0f + d0) - 1.0f/(1.0f - d0)) * sq20;
        if (j1 >= 0 && j1 < 20)
            f1 = 1.14136f * expf(2.0f - 1.0f/(1.0f + d1) - 1.0f/(1.0f - d1)) * sq20;
        j0 = j0 < 0 ? 0 : (j0 > 19 ? 19 : j0);
        j1 = j1 < 0 ? 0 : (j1 > 19 ? 19 : j1);

        if (t < 64) {
            float a = fmaf(f0, Wt1[j0*64 + t], f1 * Wt1[j1*64 + t])
                      * 0.22360679774997896f;
            h[t] = 1.679177f * a / (1.0f + expf(-a));
        }
        __syncthreads();

        // sc = 1/8 (w norm) * 1/4 (inv) * 1/sqrt(8) (neighbor norm)
        const float sc = 0.011048543456039806f;
        for (int e2 = t; e2 < TENT; e2 += 256) {
            int i = e2 / 24;
            int c = e2 - i * 24;
            float v = 0.f;
            if (c < 22) {
                int widx = (c < 16) ? (i*16 + c)
                         : (c < 20) ? (256 + i*4 + (c - 16))
                                    : (320 + i*2 + (c - 20));
                // 4 independent accumulator chains (ILP for the L2 loads)
                float v0 = 0.f, v1 = 0.f, v2 = 0.f, v3 = 0.f;
                for (int k = 0; k < 64; k += 4) {
                    v0 = fmaf(h[k+0], Wt2[(k+0)*352 + widx], v0);
                    v1 = fmaf(h[k+1], Wt2[(k+1)*352 + widx], v1);
                    v2 = fmaf(h[k+2], Wt2[(k+2)*352 + widx], v2);
                    v3 = fmaf(h[k+3], Wt2[(k+3)*352 + widx], v3);
                }
                v = ((v0 + v1) + (v2 + v3)) * sc;   // fixed order: deterministic
            }
            T[(size_t)entry * TENT + e2] = v;
        }
    } else {
        // ---- count + geometry part: 2 edges per thread ----
        for (int b = t; b < NBINS; b += 256) hist[b] = 0;
        __syncthreads();

        int e0 = (blockIdx.x - TBLOCKS) * 512 + t;
        int e1 = e0 + 256;

        // interleaved independent loads (2x memory-level parallelism)
        int s0i = ei[e0];
        int s1i = ei[e1];
        int d0i = ei[N_EDGES + e0];
        int d1i = ei[N_EDGES + e1];

        float ax = pos[d0i*3+0], bx = pos[s0i*3+0];
        float cx = pos[d1i*3+0], dx = pos[s1i*3+0];
        float ay = pos[d0i*3+1], by = pos[s0i*3+1];
        float cy = pos[d1i*3+1], dy = pos[s1i*3+1];
        float az = pos[d0i*3+2], bz = pos[s0i*3+2];
        float cz = pos[d1i*3+2], dz = pos[s1i*3+2];

        float px0 = ax - bx, py0 = ay - by, pz0 = az - bz;
        float px1 = cx - dx, py1 = cy - dy, pz1 = cz - dz;
        float dist0 = sqrtf(px0*px0 + py0*py0 + pz0*pz0 + 1e-12f);
        float dist1 = sqrtf(px1*px1 + py1*py1 + pz1*pz1 + 1e-12f);
        float ri0 = 1.0f / dist0;
        float ri1 = 1.0f / dist1;
        float tt0 = dist0 * 4.2f;
        float tt1 = dist1 * 4.2f;
        evec[e0] = make_float4(px0*ri0, py0*ri0, pz0*ri0, tt0);
        evec[e1] = make_float4(px1*ri1, py1*ri1, pz1*ri1, tt1);

        int bin0, bin1;
        if (!(tt0 < 21.0f)) {
            bin0 = NBINS - 1;
        } else {
            int mm = (int)tt0;
            float gf = (tt0 - (float)mm) * (float)TGRID;
            int g0 = (int)gf; if (g0 > TGRID-1) g0 = TGRID-1;
            bin0 = mm * TGRID + g0;
            atomicAdd(&cd[d0i], 1);
        }
        if (!(tt1 < 21.0f)) {
            bin1 = NBINS - 1;
        } else {
            int mm = (int)tt1;
            float gf = (tt1 - (float)mm) * (float)TGRID;
            int g0 = (int)gf; if (g0 > TGRID-1) g0 = TGRID-1;
            bin1 = mm * TGRID + g0;
            atomicAdd(&cd[d1i], 1);
        }
        ebin[e0] = bin0;
        ebin[e1] = bin1;
        atomicAdd(&hist[bin0], 1);
        atomicAdd(&hist[bin1], 1);
        __syncthreads();

        for (int b = t; b < NBINS; b += 256) {
            int c = hist[b];
            if (c) atomicAdd(&cb[b], c);
        }
    }
}

// dual scan: block 0 scans (c0,s0), block 1 scans (c1,s1). 32768 each.
__global__ __launch_bounds__(1024) void scan2_kernel(
    int* __restrict__ c0, int* __restrict__ s0arr,
    int* __restrict__ c1, int* __restrict__ s1arr)
{
    int* cursor = (blockIdx.x == 0) ? c0 : c1;
    int* start  = (blockIdx.x == 0) ? s0arr : s1arr;
    __shared__ int partial[1024];
    int tid = threadIdx.x;
    int base = tid * 32;
    int v[32];
    int s = 0;
    #pragma unroll
    for (int j = 0; j < 32; ++j) { v[j] = cursor[base + j]; s += v[j]; }
    partial[tid] = s;
    __syncthreads();
    for (int off = 1; off < 1024; off <<= 1) {
        int t = (tid >= off) ? partial[tid - off] : 0;
        __syncthreads();
        partial[tid] += t;
        __syncthreads();
    }
    int run = (tid > 0) ? partial[tid - 1] : 0;
    #pragma unroll
    for (int j = 0; j < 32; ++j) {
        start[base + j] = run;
        cursor[base + j] = run;
        run += v[j];
    }
    if (tid == 1023) start[32768] = run;
}

// ---------------- fill: bins slots AND dst slots ---------------------------
// Also allocates the dst-side slot (32k-address atomics, cheap per r8) and
// writes elist2 = {edge id, tp row}: removes the scattered atomic + store
// from the hot edge kernel entirely.
__global__ __launch_bounds__(256) void fill_bins_kernel(
    const int* __restrict__ ebin, const int* __restrict__ ei,
    int* __restrict__ cursor_bin,            // pre-scanned starts, consumed
    int* __restrict__ cursor_dst,            // pre-scanned starts, consumed
    int4* __restrict__ binfo, int2* __restrict__ elist2)
{
    __shared__ int hist[NBINS];
    __shared__ int rbase[NBINS];
    for (int b = threadIdx.x; b < NBINS; b += 256) hist[b] = 0;
    __syncthreads();

    int e = blockIdx.x * 256 + threadIdx.x;
    int bin = ebin[e];
    atomicAdd(&hist[bin], 1);
    __syncthreads();

    for (int b = threadIdx.x; b < NBINS; b += 256) {
        int c = hist[b];
        if (c) rbase[b] = atomicAdd(&cursor_bin[b], c);  // distinct addrs/wave
        hist[b] = 0;                                     // reuse as local cursor
    }
    __syncthreads();

    int lr = atomicAdd(&hist[bin], 1);       // LDS local rank
    int slot = rbase[bin] + lr;
    int dst = ei[N_EDGES + e];
    binfo[slot] = make_int4(e, ei[e], dst, 0);

    if (bin != NBINS - 1) {                  // in-range: allocate dst slot
        int ds = atomicAdd(&cursor_dst[dst], 1);
        elist2[ds] = make_int2(e, slot);
    }
}

// ---------------- Kernel 3: binned per-edge — pure compute + stores -------
__global__ __launch_bounds__(256) void edge_table_binned(
    const float4* __restrict__ evec,
    const float* __restrict__ T, const float* __restrict__ znode,
    const int4* __restrict__ binfo,
    unsigned short* __restrict__ tp)
{
    int idx = blockIdx.x * 256 + threadIdx.x;
    int4 bf = binfo[idx];
    int e   = bf.x;
    int src = bf.y;

    float4 ev = evec[e];
    float tt = ev.w;
    if (!(tt < 21.0f)) return;       // zero message: row never read

    uint4* d4 = (uint4*)(tp + (size_t)idx * TPW);   // binned layout

    float ux = ev.x, uy = ev.y, uz = ev.z;

    int m  = (int)tt;                // 0..20
    float d0 = tt - (float)m;
    float gf = d0 * (float)TGRID;
    int g0 = (int)gf; if (g0 > TGRID-1) g0 = TGRID-1;
    float fr = gf - (float)g0;

    const float4* r0 = (const float4*)(T + (size_t)(m*65 + g0) * TENT);
    const float4* r1 = r0 + (TENT/4);    // next d0 grid point (contiguous)

    // aligned vector z loads
    const float4* zp = (const float4*)(znode + (size_t)src * 16);
    float4 zq0 = zp[0], zq1 = zp[1], zq2 = zp[2], zq3 = zp[3];
    float z[16] = {zq0.x, zq0.y, zq0.z, zq0.w,
                   zq1.x, zq1.y, zq1.z, zq1.w,
                   zq2.x, zq2.y, zq2.z, zq2.w,
                   zq3.x, zq3.y, zq3.z, zq3.w};

    float acc[24];
    #pragma unroll
    for (int c = 0; c < 24; ++c) acc[c] = 0.f;

    #pragma unroll
    for (int i = 0; i < 16; ++i) {
        float zi = z[i];
        #pragma unroll
        for (int q = 0; q < 6; ++q) {
            float4 v0 = r0[i*6 + q];
            float4 v1 = r1[i*6 + q];
            float w;
            w = fmaf(fr, v1.x - v0.x, v0.x); acc[q*4+0] = fmaf(zi, w, acc[q*4+0]);
            w = fmaf(fr, v1.y - v0.y, v0.y); acc[q*4+1] = fmaf(zi, w, acc[q*4+1]);
            w = fmaf(fr, v1.z - v0.z, v0.z); acc[q*4+2] = fmaf(zi, w, acc[q*4+2]);
            w = fmaf(fr, v1.w - v0.w, v0.w); acc[q*4+3] = fmaf(zi, w, acc[q*4+3]);
        }
    }

    float vals[38];
    #pragma unroll
    for (int c = 0; c < 22; ++c) vals[c] = acc[c];

    const float s3  = 1.7320508075688772f;
    const float s15 = 3.872983346207417f;
    const float s5  = 2.23606797749979f;
    float sh1x = s3*ux, sh1y = s3*uy, sh1z = s3*uz;
    float sh2a = s15 * ux * uz;
    float sh2b = s15 * ux * uy;
    float sh2c = s5 * (uy*uy - 0.5f*(ux*ux + uz*uz));
    float sh2d = s15 * uy * uz;
    float sh2e = 0.5f * s15 * (uz*uz - ux*ux);

    // expand T first (consumes vals[20..21]), then V descending (16..19)
    #pragma unroll
    for (int u = 1; u >= 0; --u) {
        float v = vals[20 + u];
        vals[28 + u*5 + 0] = v * sh2a;
        vals[28 + u*5 + 1] = v * sh2b;
        vals[28 + u*5 + 2] = v * sh2c;
        vals[28 + u*5 + 3] = v * sh2d;
        vals[28 + u*5 + 4] = v * sh2e;
    }
    #pragma unroll
    for (int u = 3; u >= 0; --u) {
        float v = vals[16 + u];
        vals[16 + u*3 + 0] = v * sh1x;
        vals[16 + u*3 + 1] = v * sh1y;
        vals[16 + u*3 + 2] = v * sh1z;
    }

    // fp16 pack; store each uint4 immediately (short live ranges)
    d4[0] = make_uint4(pkh(vals[0], vals[1]),  pkh(vals[2], vals[3]),
                       pkh(vals[4], vals[5]),  pkh(vals[6], vals[7]));
    d4[1] = make_uint4(pkh(vals[8], vals[9]),  pkh(vals[10], vals[11]),
                       pkh(vals[12], vals[13]),pkh(vals[14], vals[15]));
    d4[2] = make_uint4(pkh(vals[16], vals[17]),pkh(vals[18], vals[19]),
                       pkh(vals[20], vals[21]),pkh(vals[22], vals[23]));
    d4[3] = make_uint4(pkh(vals[24], vals[25]),pkh(vals[26], vals[27]),
                       pkh(vals[28], vals[29]),pkh(vals[30], vals[31]));
    d4[4] = make_uint4(pkh(vals[32], vals[33]),pkh(vals[34], vals[35]),
                       pkh(vals[36], vals[37]),0);
}

// ---------------- Kernel 4: gather segment-sum, SORTED (deterministic) ------
__global__ __launch_bounds__(256) void gather_sorted_kernel(
    const unsigned short* __restrict__ tp, const int* __restrict__ start,
    const int2* __restrict__ elist2, float* __restrict__ out)
{
    __shared__ int sid[4][128];
    __shared__ int srw[4][128];
    __shared__ int so[4][128];
    int wave = threadIdx.x >> 6;
    int lane = threadIdx.x & 63;
    int n = blockIdx.x * 4 + wave;          // grid == N_NODES/4, always valid
    int s0 = start[n], s1 = start[n+1];
    int K = s1 - s0;
    bool small = (K <= 128);

    if (small) {
        for (int j = lane; j < K; j += 64) {
            int2 v = elist2[s0 + j];
            sid[wave][j] = v.x;
            srw[wave][j] = v.y;
        }
    }
    __syncthreads();
    if (small) {
        for (int j = lane; j < K; j += 64) {
            int v = sid[wave][j];
            int r = 0;
            for (int q = 0; q < K; ++q) r += (sid[wave][q] < v);
            so[wave][r] = srw[wave][j];   // edge ids distinct -> permutation
        }
    }
    __syncthreads();

    if (lane < 19) {
        float acc0 = 0.f, acc1 = 0.f;
        if (small) {
            for (int j = 0; j < K; ++j) {
                const unsigned* row = (const unsigned*)
                    (tp + (size_t)so[wave][j] * TPW);
                unsigned v = row[lane];
                acc0 += __half2float(__ushort_as_half((unsigned short)(v & 0xffffu)));
                acc1 += __half2float(__ushort_as_half((unsigned short)(v >> 16)));
            }
        } else {
            for (int j = s0; j < s1; ++j) {
                int2 ev = elist2[j];
                const unsigned* row = (const unsigned*)
                    (tp + (size_t)ev.y * TPW);
                unsigned v = row[lane];
                acc0 += __half2float(__ushort_as_half((unsigned short)(v & 0xffffu)));
                acc1 += __half2float(__ushort_as_half((unsigned short)(v >> 16)));
            }
        }
        out[n*OUTC + 16 + 2*lane] = acc0;
        out[n*OUTC + 16 + 2*lane + 1] = acc1;
    }
}

// ---------------- fallback (atomics) if ws too small -----------------
__global__ __launch_bounds__(256) void node_emb_fb_kernel(
    const float* __restrict__ x, const float* __restrict__ W1,
    const float* __restrict__ W2, float* __restrict__ out)
{
    int n = blockIdx.x * blockDim.x + threadIdx.x;
    if (n >= N_NODES) return;
    const float inv10 = 0.31622776601683794f;
    const float inv64 = 0.125f;
    float xr[10];
    #pragma unroll
    for (int i = 0; i < 10; ++i) xr[i] = x[n*10 + i];
    float t[64];
    #pragma unroll
    for (int k = 0; k < 64; ++k) {
        float acc = 0.f;
        #pragma unroll
        for (int i = 0; i < 10; ++i) acc = fmaf(xr[i], W1[i*64 + k], acc);
        t[k] = acc * inv10;
    }
    float e[16];
    #pragma unroll
    for (int j = 0; j < 16; ++j) e[j] = 0.f;
    #pragma unroll
    for (int k = 0; k < 64; ++k) {
        float tk = t[k];
        #pragma unroll
        for (int j = 0; j < 16; ++j) e[j] = fmaf(tk, W2[k*16 + j], e[j]);
    }
    #pragma unroll
    for (int j = 0; j < 16; ++j) out[n*OUTC + j] = e[j] * inv64;
}

__global__ __launch_bounds__(256) void edge_kernel_atomic(
    const float* __restrict__ pos, const int* __restrict__ ei,
    const float* __restrict__ Wt1, const float* __restrict__ Wt2,
    float* out)
{
    int e = blockIdx.x * blockDim.x + threadIdx.x;
    if (e >= N_EDGES) return;
    int src = ei[e];
    int dst = ei[N_EDGES + e];
    float px = pos[dst*3+0] - pos[src*3+0];
    float py = pos[dst*3+1] - pos[src*3+1];
    float pz = pos[dst*3+2] - pos[src*3+2];
    float dist = sqrtf(px*px + py*py + pz*pz + 1e-12f);
    float rinv = 1.0f / dist;
    float ux = px*rinv, uy = py*rinv, uz = pz*rinv;
    const float step = 5.0f / 21.0f;
    float tt = dist / step;
    int m  = (int)floorf(tt);
    int j0 = m - 1, j1 = m;
    float d0 = tt - (float)m, d1 = d0 - 1.0f;
    const float sq20 = 4.47213595499958f;
    float f0 = 0.f, f1 = 0.f;
    if (j0 >= 0 && j0 < 20)
        f0 = 1.14136f * expf(2.0f - 1.0f/(1.0f + d0) - 1.0f/(1.0f - d0)) * sq20;
    if (j1 >= 0 && j1 < 20 && d1 > -1.0f)
        f1 = 1.14136f * expf(2.0f - 1.0f/(1.0f + d1) - 1.0f/(1.0f - d1)) * sq20;
    if (f0 == 0.f && f1 == 0.f) return;
    j0 = j0 < 0 ? 0 : (j0 > 19 ? 19 : j0);
    j1 = j1 < 0 ? 0 : (j1 > 19 ? 19 : j1);
    const float* w1a = Wt1 + j0*64;
    const float* w1b = Wt1 + j1*64;
    float z[16];
    #pragma unroll
    for (int i = 0; i < 16; ++i) z[i] = out[src*OUTC + i];
    const float rsq20 = 0.22360679774997896f;
    const float snorm = 1.679177f;
    float accS[16], accV[4], accT[2];
    #pragma unroll
    for (int u = 0; u < 16; ++u) accS[u] = 0.f;
    #pragma unroll
    for (int u = 0; u < 4; ++u) accV[u] = 0.f;
    #pragma unroll
    for (int u = 0; u < 2; ++u) accT[u] = 0.f;
    for (int k = 0; k < 64; ++k) {
        float a = fmaf(f0, w1a[k], f1 * w1b[k]) * rsq20;
        float hk = snorm * a / (1.0f + expf(-a));
        const float* row = Wt2 + k*352;
        float tmp[16];
        #pragma unroll
        for (int u = 0; u < 16; ++u) tmp[u] = 0.f;
        #pragma unroll
        for (int i = 0; i < 16; ++i) {
            float zi = z[i];
            #pragma unroll
            for (int u = 0; u < 16; ++u) tmp[u] = fmaf(zi, row[i*16 + u], tmp[u]);
        }
        #pragma unroll
        for (int u = 0; u < 16; ++u) accS[u] = fmaf(hk, tmp[u], accS[u]);
        float tv[4] = {0.f,0.f,0.f,0.f};
        #pragma unroll
        for (int i = 0; i < 16; ++i) {
            float zi = z[i];
            #pragma unroll
            for (int u = 0; u < 4; ++u) tv[u] = fmaf(zi, row[256 + i*4 + u], tv[u]);
        }
        #pragma unroll
        for (int u = 0; u < 4; ++u) accV[u] = fmaf(hk, tv[u], accV[u]);
        float tw[2] = {0.f,0.f};
        #pragma unroll
        for (int i = 0; i < 16; ++i) {
            float zi = z[i];
            #pragma unroll
            for (int u = 0; u < 2; ++u) tw[u] = fmaf(zi, row[320 + i*2 + u], tw[u]);
        }
        #pragma unroll
        for (int u = 0; u < 2; ++u) accT[u] = fmaf(hk, tw[u], accT[u]);
    }
    const float sc = 0.125f * 0.25f * 0.35355339059327373f;
    const float s3  = 1.7320508075688772f;
    const float s15 = 3.872983346207417f;
    const float s5  = 2.23606797749979f;
    float sh1x = s3*ux, sh1y = s3*uy, sh1z = s3*uz;
    float sh2[5];
    sh2[0] = s15 * ux * uz;
    sh2[1] = s15 * ux * uy;
    sh2[2] = s5 * (uy*uy - 0.5f*(ux*ux + uz*uz));
    sh2[3] = s15 * uy * uz;
    sh2[4] = 0.5f * s15 * (uz*uz - ux*ux);
    float* orow = out + dst*OUTC + 16;
    #pragma unroll
    for (int u = 0; u < 16; ++u) atomicAdd(&orow[u], accS[u] * sc);
    #pragma unroll
    for (int u = 0; u < 4; ++u) {
        float v = accV[u] * sc;
        atomicAdd(&orow[16 + u*3 + 0], v * sh1x);
        atomicAdd(&orow[16 + u*3 + 1], v * sh1y);
        atomicAdd(&orow[16 + u*3 + 2], v * sh1z);
    }
    #pragma unroll
    for (int u = 0; u < 2; ++u) {
        float v = accT[u] * sc;
        #pragma unroll
        for (int mm = 0; mm < 5; ++mm)
            atomicAdd(&orow[28 + u*5 + mm], v * sh2[mm]);
    }
}

extern "C" void kernel_launch(void* const* d_in, const int* in_sizes, int n_in,
                              void* d_out, int out_size, void* d_ws, size_t ws_size,
                              hipStream_t stream) {
    const float* x   = (const float*)d_in[0];
    const float* pos = (const float*)d_in[1];
    const int*   ei  = (const int*)d_in[2];
    const float* We1 = (const float*)d_in[3];
    const float* We2 = (const float*)d_in[4];
    const float* Wt1 = (const float*)d_in[5];
    const float* Wt2 = (const float*)d_in[6];
    float* out = (float*)d_out;

    char* base = (char*)d_ws;
    size_t off = 0;
    unsigned short* tp = (unsigned short*)(base + off);
    off += (size_t)N_EDGES * TPW * 2;                    // fp16 rows, 21 MB
    float* T  = (float*)(base + off);       off += (size_t)TBLOCKS * TENT * 4;  // 2.1 MB
    float* znode = (float*)(base + off);    off += (size_t)N_NODES * 16 * 4;    // 2 MB
    float4* evec = (float4*)(base + off);   off += (size_t)N_EDGES * 16;        // 4 MB
    int* cursor_dst = (int*)(base + off);   off += (size_t)32768 * 4;
    int* cursor_bin = (int*)(base + off);   off += (size_t)32768 * 4;
    int* start_dst  = (int*)(base + off);   off += (size_t)32769 * 4;
    int* start_bin  = (int*)(base + off);   off += (size_t)32769 * 4;
    int* ebin       = (int*)(base + off);   off += (size_t)N_EDGES * 4;
    int4* binfo     = (int4*)(base + off);  off += (size_t)N_EDGES * 16;
    int2* elist2    = (int2*)(base + off);  off += (size_t)N_EDGES * 8;
    size_t need = off;

    if (ws_size >= need) {
        node_emb_kernel<<<N_NODES/256, 256, 0, stream>>>(x, We1, We2, out, znode,
                                                         cursor_dst, cursor_bin);
        prep_kernel<<<TBLOCKS + CBLK2, 256, 0, stream>>>(
            Wt1, Wt2, T, ei, pos, cursor_dst, cursor_bin, ebin, evec);
        scan2_kernel<<<2, 1024, 0, stream>>>(cursor_dst, start_dst,
                                             cursor_bin, start_bin);
        fill_bins_kernel<<<N_EDGES/256, 256, 0, stream>>>(ebin, ei, cursor_bin,
                                                          cursor_dst,
                                                          binfo, elist2);
        edge_table_binned<<<N_EDGES/256, 256, 0, stream>>>(evec, T, znode,
                                                           binfo, tp);
        gather_sorted_kernel<<<N_NODES/4, 256, 0, stream>>>(tp, start_dst,
                                                            elist2, out);
    } else {
        hipMemsetAsync(out, 0, (size_t)out_size * sizeof(float), stream);
        node_emb_fb_kernel<<<N_NODES/256, 256, 0, stream>>>(x, We1, We2, out);
        edge_kernel_atomic<<<N_EDGES/256, 256, 0, stream>>>(pos, ei, Wt1, Wt2, out);
    }
}

// Round 26
// 160.897 us; speedup vs baseline: 1.0210x; 1.0210x over previous
//
#include <hip/hip_runtime.h>
#include <hip/hip_fp16.h>
#include <math.h>

#define N_NODES 32768
#define N_EDGES 262144
#define OUTC 54      // 16 emb + 38 msg
#define TPW  40      // tp row stride in HALVES (38 used, 80 B, 16B-aligned)
#define TGRID 64     // d0 samples per bin (65 points incl. both ends)
#define TENT 384     // floats per table entry: 16 i * 24 padded cols
#define NBINS 1345   // 21*64 in-range bins + 1 out-of-range bin
#define TBLOCKS 1365 // 21*65 table entries
#define CBLK2 (N_EDGES/512)  // count blocks, 2 edges per thread

__device__ __forceinline__ unsigned pkh(float a, float b) {
    auto r = __builtin_amdgcn_cvt_pkrtz(a, b);   // v_cvt_pkrtz_f16_f32
    union { decltype(r) v; unsigned u; } cv;
    cv.v = r;
    return cv.u;
}

// ---------------- Kernel 1: node embeddings + cursor zeroing --------------
__global__ __launch_bounds__(256) void node_emb_kernel(
    const float* __restrict__ x, const float* __restrict__ W1,
    const float* __restrict__ W2, float* __restrict__ out,
    float* __restrict__ znode,
    int* __restrict__ cursor_dst, int* __restrict__ cursor_bin)
{
    int n = blockIdx.x * blockDim.x + threadIdx.x;
    if (n >= N_NODES) return;
    cursor_dst[n] = 0;
    cursor_bin[n] = 0;

    const float inv10 = 0.31622776601683794f;
    const float inv64 = 0.125f;

    float xr[10];
    #pragma unroll
    for (int i = 0; i < 10; ++i) xr[i] = x[n*10 + i];

    float t[64];
    #pragma unroll
    for (int k = 0; k < 64; ++k) {
        float acc = 0.f;
        #pragma unroll
        for (int i = 0; i < 10; ++i) acc = fmaf(xr[i], W1[i*64 + k], acc);
        t[k] = acc * inv10;
    }

    float e[16];
    #pragma unroll
    for (int j = 0; j < 16; ++j) e[j] = 0.f;
    #pragma unroll
    for (int k = 0; k < 64; ++k) {
        float tk = t[k];
        #pragma unroll
        for (int j = 0; j < 16; ++j) e[j] = fmaf(tk, W2[k*16 + j], e[j]);
    }
    float4* zb = (float4*)(znode + (size_t)n * 16);
    #pragma unroll
    for (int q = 0; q < 4; ++q) {
        float4 v = make_float4(e[q*4+0]*inv64, e[q*4+1]*inv64,
                               e[q*4+2]*inv64, e[q*4+3]*inv64);
        zb[q] = v;
        out[n*OUTC + q*4 + 0] = v.x;
        out[n*OUTC + q*4 + 1] = v.y;
        out[n*OUTC + q*4 + 2] = v.z;
        out[n*OUTC + q*4 + 3] = v.w;
    }
}

// ---------------- prep: fused table-build (blocks 0..1364) ---------------
//                  + count/geometry (blocks 1365.., 2 edges/thread) --------
__global__ __launch_bounds__(256) void prep_kernel(
    const float* __restrict__ Wt1, const float* __restrict__ Wt2,
    float* __restrict__ T,
    const int* __restrict__ ei, const float* __restrict__ pos,
    int* __restrict__ cd, int* __restrict__ cb, int* __restrict__ ebin,
    float4* __restrict__ evec)
{
    __shared__ int hist[NBINS];
    __shared__ float h[64];
    int t = threadIdx.x;

    if (blockIdx.x < TBLOCKS) {
        // ---- table part ----
        int entry = blockIdx.x;            // 0 .. 21*65-1
        int m = entry / 65;
        int g = entry - m * 65;
        float d0 = (float)g * (1.0f / TGRID);
        float d1 = d0 - 1.0f;
        int j0 = m - 1, j1 = m;
        const float sq20 = 4.47213595499958f;

        float f0 = 0.f, f1 = 0.f;
        if (j0 >= 0 && j0 < 20)
            f0 = 1.14136f * expf(2.0f - 1.0f/(1.0f + d0) - 1.0f/(1.0f - d0)) * sq20;
        if (j1 >= 0 && j1 < 20)
            f1 = 1.14136f * expf(2.0f - 1.0f/(1.0f + d1) - 1.0f/(1.0f - d1)) * sq20;
        j0 = j0 < 0 ? 0 : (j0 > 19 ? 19 : j0);
        j1 = j1 < 0 ? 0 : (j1 > 19 ? 19 : j1);

        if (t < 64) {
            float a = fmaf(f0, Wt1[j0*64 + t], f1 * Wt1[j1*64 + t])
                      * 0.22360679774997896f;
            h[t] = 1.679177f * a / (1.0f + expf(-a));
        }
        __syncthreads();

        // sc = 1/8 (w norm) * 1/4 (inv) * 1/sqrt(8) (neighbor norm)
        const float sc = 0.011048543456039806f;
        for (int e2 = t; e2 < TENT; e2 += 256) {
            int i = e2 / 24;
            int c = e2 - i * 24;
            float v = 0.f;
            if (c < 22) {
                int widx = (c < 16) ? (i*16 + c)
                         : (c < 20) ? (256 + i*4 + (c - 16))
                                    : (320 + i*2 + (c - 20));
                // 4 independent accumulator chains (ILP for the L2 loads)
                float v0 = 0.f, v1 = 0.f, v2 = 0.f, v3 = 0.f;
                for (int k = 0; k < 64; k += 4) {
                    v0 = fmaf(h[k+0], Wt2[(k+0)*352 + widx], v0);
                    v1 = fmaf(h[k+1], Wt2[(k+1)*352 + widx], v1);
                    v2 = fmaf(h[k+2], Wt2[(k+2)*352 + widx], v2);
                    v3 = fmaf(h[k+3], Wt2[(k+3)*352 + widx], v3);
                }
                v = ((v0 + v1) + (v2 + v3)) * sc;   // fixed order: deterministic
            }
            T[(size_t)entry * TENT + e2] = v;
        }
    } else {
        // ---- count + geometry part: 2 edges per thread ----
        for (int b = t; b < NBINS; b += 256) hist[b] = 0;
        __syncthreads();

        int e0 = (blockIdx.x - TBLOCKS) * 512 + t;
        int e1 = e0 + 256;

        // interleaved independent loads (2x memory-level parallelism)
        int s0i = ei[e0];
        int s1i = ei[e1];
        int d0i = ei[N_EDGES + e0];
        int d1i = ei[N_EDGES + e1];

        float ax = pos[d0i*3+0], bx = pos[s0i*3+0];
        float cx = pos[d1i*3+0], dx = pos[s1i*3+0];
        float ay = pos[d0i*3+1], by = pos[s0i*3+1];
        float cy = pos[d1i*3+1], dy = pos[s1i*3+1];
        float az = pos[d0i*3+2], bz = pos[s0i*3+2];
        float cz = pos[d1i*3+2], dz = pos[s1i*3+2];

        float px0 = ax - bx, py0 = ay - by, pz0 = az - bz;
        float px1 = cx - dx, py1 = cy - dy, pz1 = cz - dz;
        float dist0 = sqrtf(px0*px0 + py0*py0 + pz0*pz0 + 1e-12f);
        float dist1 = sqrtf(px1*px1 + py1*py1 + pz1*pz1 + 1e-12f);
        float ri0 = 1.0f / dist0;
        float ri1 = 1.0f / dist1;
        float tt0 = dist0 * 4.2f;
        float tt1 = dist1 * 4.2f;
        evec[e0] = make_float4(px0*ri0, py0*ri0, pz0*ri0, tt0);
        evec[e1] = make_float4(px1*ri1, py1*ri1, pz1*ri1, tt1);

        int bin0, bin1;
        if (!(tt0 < 21.0f)) {
            bin0 = NBINS - 1;
        } else {
            int mm = (int)tt0;
            float gf = (tt0 - (float)mm) * (float)TGRID;
            int g0 = (int)gf; if (g0 > TGRID-1) g0 = TGRID-1;
            bin0 = mm * TGRID + g0;
            atomicAdd(&cd[d0i], 1);
        }
        if (!(tt1 < 21.0f)) {
            bin1 = NBINS - 1;
        } else {
            int mm = (int)tt1;
            float gf = (tt1 - (float)mm) * (float)TGRID;
            int g0 = (int)gf; if (g0 > TGRID-1) g0 = TGRID-1;
            bin1 = mm * TGRID + g0;
            atomicAdd(&cd[d1i], 1);
        }
        ebin[e0] = bin0;
        ebin[e1] = bin1;
        atomicAdd(&hist[bin0], 1);
        atomicAdd(&hist[bin1], 1);
        __syncthreads();

        for (int b = t; b < NBINS; b += 256) {
            int c = hist[b];
            if (c) atomicAdd(&cb[b], c);
        }
    }
}

// dual scan: block 0 scans (c0,s0), block 1 scans (c1,s1). 32768 each.
__global__ __launch_bounds__(1024) void scan2_kernel(
    int* __restrict__ c0, int* __restrict__ s0arr,
    int* __restrict__ c1, int* __restrict__ s1arr)
{
    int* cursor = (blockIdx.x == 0) ? c0 : c1;
    int* start  = (blockIdx.x == 0) ? s0arr : s1arr;
    __shared__ int partial[1024];
    int tid = threadIdx.x;
    int base = tid * 32;
    int v[32];
    int s = 0;
    #pragma unroll
    for (int j = 0; j < 32; ++j) { v[j] = cursor[base + j]; s += v[j]; }
    partial[tid] = s;
    __syncthreads();
    for (int off = 1; off < 1024; off <<= 1) {
        int t = (tid >= off) ? partial[tid - off] : 0;
        __syncthreads();
        partial[tid] += t;
        __syncthreads();
    }
    int run = (tid > 0) ? partial[tid - 1] : 0;
    #pragma unroll
    for (int j = 0; j < 32; ++j) {
        start[base + j] = run;
        cursor[base + j] = run;
        run += v[j];
    }
    if (tid == 1023) start[32768] = run;
}

// ---------------- fill: two-level; emits int4 {e, src, dst, 0} ------------
__global__ __launch_bounds__(256) void fill_bins_kernel(
    const int* __restrict__ ebin, const int* __restrict__ ei,
    int* __restrict__ cursor_bin,            // pre-scanned starts, consumed
    int4* __restrict__ binfo)
{
    __shared__ int hist[NBINS];
    __shared__ int rbase[NBINS];
    for (int b = threadIdx.x; b < NBINS; b += 256) hist[b] = 0;
    __syncthreads();

    int e = blockIdx.x * 256 + threadIdx.x;
    int bin = ebin[e];
    atomicAdd(&hist[bin], 1);
    __syncthreads();

    for (int b = threadIdx.x; b < NBINS; b += 256) {
        int c = hist[b];
        if (c) rbase[b] = atomicAdd(&cursor_bin[b], c);  // distinct addrs/wave
        hist[b] = 0;                                     // reuse as local cursor
    }
    __syncthreads();

    int lr = atomicAdd(&hist[bin], 1);       // LDS local rank
    int slot = rbase[bin] + lr;
    binfo[slot] = make_int4(e, ei[e], ei[N_EDGES + e], 0);
}

// ---------------- Kernel 3: binned per-edge, fused lerp -------------------
__global__ __launch_bounds__(256) void edge_table_binned(
    const float4* __restrict__ evec,
    const float* __restrict__ T, const float* __restrict__ znode,
    const int4* __restrict__ binfo,
    unsigned short* __restrict__ tp, int* __restrict__ cursor,
    int2* __restrict__ elist2)
{
    int idx = blockIdx.x * 256 + threadIdx.x;
    int4 bf = binfo[idx];
    int e   = bf.x;
    int src = bf.y;
    int dst = bf.z;

    float4 ev = evec[e];
    float tt = ev.w;
    if (!(tt < 21.0f)) return;       // zero message, not in dst counts

    int slot = atomicAdd(&cursor[dst], 1);
    elist2[slot] = make_int2(e, idx);

    uint4* d4 = (uint4*)(tp + (size_t)idx * TPW);   // binned layout

    float ux = ev.x, uy = ev.y, uz = ev.z;

    int m  = (int)tt;                // 0..20
    float d0 = tt - (float)m;
    float gf = d0 * (float)TGRID;
    int g0 = (int)gf; if (g0 > TGRID-1) g0 = TGRID-1;
    float fr = gf - (float)g0;

    const float4* r0 = (const float4*)(T + (size_t)(m*65 + g0) * TENT);
    const float4* r1 = r0 + (TENT/4);    // next d0 grid point (contiguous)

    // aligned vector z loads
    const float4* zp = (const float4*)(znode + (size_t)src * 16);
    float4 zq0 = zp[0], zq1 = zp[1], zq2 = zp[2], zq3 = zp[3];
    float z[16] = {zq0.x, zq0.y, zq0.z, zq0.w,
                   zq1.x, zq1.y, zq1.z, zq1.w,
                   zq2.x, zq2.y, zq2.z, zq2.w,
                   zq3.x, zq3.y, zq3.z, zq3.w};

    float acc[24];
    #pragma unroll
    for (int c = 0; c < 24; ++c) acc[c] = 0.f;

    #pragma unroll
    for (int i = 0; i < 16; ++i) {
        float zi = z[i];
        #pragma unroll
        for (int q = 0; q < 6; ++q) {
            float4 v0 = r0[i*6 + q];
            float4 v1 = r1[i*6 + q];
            float w;
            w = fmaf(fr, v1.x - v0.x, v0.x); acc[q*4+0] = fmaf(zi, w, acc[q*4+0]);
            w = fmaf(fr, v1.y - v0.y, v0.y); acc[q*4+1] = fmaf(zi, w, acc[q*4+1]);
            w = fmaf(fr, v1.z - v0.z, v0.z); acc[q*4+2] = fmaf(zi, w, acc[q*4+2]);
            w = fmaf(fr, v1.w - v0.w, v0.w); acc[q*4+3] = fmaf(zi, w, acc[q*4+3]);
        }
    }

    float vals[38];
    #pragma unroll
    for (int c = 0; c < 22; ++c) vals[c] = acc[c];

    const float s3  = 1.7320508075688772f;
    const float s15 = 3.872983346207417f;
    const float s5  = 2.23606797749979f;
    float sh1x = s3*ux, sh1y = s3*uy, sh1z = s3*uz;
    float sh2a = s15 * ux * uz;
    float sh2b = s15 * ux * uy;
    float sh2c = s5 * (uy*uy - 0.5f*(ux*ux + uz*uz));
    float sh2d = s15 * uy * uz;
    float sh2e = 0.5f * s15 * (uz*uz - ux*ux);

    // expand T first (consumes vals[20..21]), then V descending (16..19)
    #pragma unroll
    for (int u = 1; u >= 0; --u) {
        float v = vals[20 + u];
        vals[28 + u*5 + 0] = v * sh2a;
        vals[28 + u*5 + 1] = v * sh2b;
        vals[28 + u*5 + 2] = v * sh2c;
        vals[28 + u*5 + 3] = v * sh2d;
        vals[28 + u*5 + 4] = v * sh2e;
    }
    #pragma unroll
    for (int u = 3; u >= 0; --u) {
        float v = vals[16 + u];
        vals[16 + u*3 + 0] = v * sh1x;
        vals[16 + u*3 + 1] = v * sh1y;
        vals[16 + u*3 + 2] = v * sh1z;
    }

    // fp16 pack; store each uint4 immediately (short live ranges)
    d4[0] = make_uint4(pkh(vals[0], vals[1]),  pkh(vals[2], vals[3]),
                       pkh(vals[4], vals[5]),  pkh(vals[6], vals[7]));
    d4[1] = make_uint4(pkh(vals[8], vals[9]),  pkh(vals[10], vals[11]),
                       pkh(vals[12], vals[13]),pkh(vals[14], vals[15]));
    d4[2] = make_uint4(pkh(vals[16], vals[17]),pkh(vals[18], vals[19]),
                       pkh(vals[20], vals[21]),pkh(vals[22], vals[23]));
    d4[3] = make_uint4(pkh(vals[24], vals[25]),pkh(vals[26], vals[27]),
                       pkh(vals[28], vals[29]),pkh(vals[30], vals[31]));
    d4[4] = make_uint4(pkh(vals[32], vals[33]),pkh(vals[34], vals[35]),
                       pkh(vals[36], vals[37]),0);
}

// ---------------- Kernel 4: gather segment-sum, SORTED (deterministic) ------
__global__ __launch_bounds__(256) void gather_sorted_kernel(
    const unsigned short* __restrict__ tp, const int* __restrict__ start,
    const int2* __restrict__ elist2, float* __restrict__ out)
{
    __shared__ int sid[4][128];
    __shared__ int srw[4][128];
    __shared__ int so[4][128];
    int wave = threadIdx.x >> 6;
    int lane = threadIdx.x & 63;
    int n = blockIdx.x * 4 + wave;          // grid == N_NODES/4, always valid
    int s0 = start[n], s1 = start[n+1];
    int K = s1 - s0;
    bool small = (K <= 128);

    if (small) {
        for (int j = lane; j < K; j += 64) {
            int2 v = elist2[s0 + j];
            sid[wave][j] = v.x;
            srw[wave][j] = v.y;
        }
    }
    __syncthreads();
    if (small) {
        for (int j = lane; j < K; j += 64) {
            int v = sid[wave][j];
            int r = 0;
            for (int q = 0; q < K; ++q) r += (sid[wave][q] < v);
            so[wave][r] = srw[wave][j];   // edge ids distinct -> permutation
        }
    }
    __syncthreads();

    if (lane < 19) {
        float acc0 = 0.f, acc1 = 0.f;
        if (small) {
            for (int j = 0; j < K; ++j) {
                const unsigned* row = (const unsigned*)
                    (tp + (size_t)so[wave][j] * TPW);
                unsigned v = row[lane];
                acc0 += __half2float(__ushort_as_half((unsigned short)(v & 0xffffu)));
                acc1 += __half2float(__ushort_as_half((unsigned short)(v >> 16)));
            }
        } else {
            for (int j = s0; j < s1; ++j) {
                int2 ev = elist2[j];
                const unsigned* row = (const unsigned*)
                    (tp + (size_t)ev.y * TPW);
                unsigned v = row[lane];
                acc0 += __half2float(__ushort_as_half((unsigned short)(v & 0xffffu)));
                acc1 += __half2float(__ushort_as_half((unsigned short)(v >> 16)));
            }
        }
        out[n*OUTC + 16 + 2*lane] = acc0;
        out[n*OUTC + 16 + 2*lane + 1] = acc1;
    }
}

// ---------------- fallback (atomics) if ws too small -----------------
__global__ __launch_bounds__(256) void node_emb_fb_kernel(
    const float* __restrict__ x, const float* __restrict__ W1,
    const float* __restrict__ W2, float* __restrict__ out)
{
    int n = blockIdx.x * blockDim.x + threadIdx.x;
    if (n >= N_NODES) return;
    const float inv10 = 0.31622776601683794f;
    const float inv64 = 0.125f;
    float xr[10];
    #pragma unroll
    for (int i = 0; i < 10; ++i) xr[i] = x[n*10 + i];
    float t[64];
    #pragma unroll
    for (int k = 0; k < 64; ++k) {
        float acc = 0.f;
        #pragma unroll
        for (int i = 0; i < 10; ++i) acc = fmaf(xr[i], W1[i*64 + k], acc);
        t[k] = acc * inv10;
    }
    float e[16];
    #pragma unroll
    for (int j = 0; j < 16; ++j) e[j] = 0.f;
    #pragma unroll
    for (int k = 0; k < 64; ++k) {
        float tk = t[k];
        #pragma unroll
        for (int j = 0; j < 16; ++j) e[j] = fmaf(tk, W2[k*16 + j], e[j]);
    }
    #pragma unroll
    for (int j = 0; j < 16; ++j) out[n*OUTC + j] = e[j] * inv64;
}

__global__ __launch_bounds__(256) void edge_kernel_atomic(
    const float* __restrict__ pos, const int* __restrict__ ei,
    const float* __restrict__ Wt1, const float* __restrict__ Wt2,
    float* out)
{
    int e = blockIdx.x * blockDim.x + threadIdx.x;
    if (e >= N_EDGES) return;
    int src = ei[e];
    int dst = ei[N_EDGES + e];
    float px = pos[dst*3+0] - pos[src*3+0];
    float py = pos[dst*3+1] - pos[src*3+1];
    float pz = pos[dst*3+2] - pos[src*3+2];
    float dist = sqrtf(px*px + py*py + pz*pz + 1e-12f);
    float rinv = 1.0f / dist;
    float ux = px*rinv, uy = py*rinv, uz = pz*rinv;
    const float step = 5.0f / 21.0f;
    float tt = dist / step;
    int m  = (int)floorf(tt);
    int j0 = m - 1, j1 = m;
    float d0 = tt - (float)m, d1 = d0 - 1.0f;
    const float sq20 = 4.47213595499958f;
    float f0 = 0.f, f1 = 0.f;
    if (j0 >= 0 && j0 < 20)
        f0 = 1.14136f * expf(2.0f - 1.0f/(1.0f + d0) - 1.0f/(1.0f - d0)) * sq20;
    if (j1 >= 0 && j1 < 20 && d1 > -1.0f)
        f1 = 1.14136f * expf(2.0f - 1.0f/(1.0f + d1) - 1.0f/(1.0f - d1)) * sq20;
    if (f0 == 0.f && f1 == 0.f) return;
    j0 = j0 < 0 ? 0 : (j0 > 19 ? 19 : j0);
    j1 = j1 < 0 ? 0 : (j1 > 19 ? 19 : j1);
    const float* w1a = Wt1 + j0*64;
    const float* w1b = Wt1 + j1*64;
    float z[16];
    #pragma unroll
    for (int i = 0; i < 16; ++i) z[i] = out[src*OUTC + i];
    const float rsq20 = 0.22360679774997896f;
    const float snorm = 1.679177f;
    float accS[16], accV[4], accT[2];
    #pragma unroll
    for (int u = 0; u < 16; ++u) accS[u] = 0.f;
    #pragma unroll
    for (int u = 0; u < 4; ++u) accV[u] = 0.f;
    #pragma unroll
    for (int u = 0; u < 2; ++u) accT[u] = 0.f;
    for (int k = 0; k < 64; ++k) {
        float a = fmaf(f0, w1a[k], f1 * w1b[k]) * rsq20;
        float hk = snorm * a / (1.0f + expf(-a));
        const float* row = Wt2 + k*352;
        float tmp[16];
        #pragma unroll
        for (int u = 0; u < 16; ++u) tmp[u] = 0.f;
        #pragma unroll
        for (int i = 0; i < 16; ++i) {
            float zi = z[i];
            #pragma unroll
            for (int u = 0; u < 16; ++u) tmp[u] = fmaf(zi, row[i*16 + u], tmp[u]);
        }
        #pragma unroll
        for (int u = 0; u < 16; ++u) accS[u] = fmaf(hk, tmp[u], accS[u]);
        float tv[4] = {0.f,0.f,0.f,0.f};
        #pragma unroll
        for (int i = 0; i < 16; ++i) {
            float zi = z[i];
            #pragma unroll
            for (int u = 0; u < 4; ++u) tv[u] = fmaf(zi, row[256 + i*4 + u], tv[u]);
        }
        #pragma unroll
        for (int u = 0; u < 4; ++u) accV[u] = fmaf(hk, tv[u], accV[u]);
        float tw[2] = {0.f,0.f};
        #pragma unroll
        for (int i = 0; i < 16; ++i) {
            float zi = z[i];
            #pragma unroll
            for (int u = 0; u < 2; ++u) tw[u] = fmaf(zi, row[320 + i*2 + u], tw[u]);
        }
        #pragma unroll
        for (int u = 0; u < 2; ++u) accT[u] = fmaf(hk, tw[u], accT[u]);
    }
    const float sc = 0.125f * 0.25f * 0.35355339059327373f;
    const float s3  = 1.7320508075688772f;
    const float s15 = 3.872983346207417f;
    const float s5  = 2.23606797749979f;
    float sh1x = s3*ux, sh1y = s3*uy, sh1z = s3*uz;
    float sh2[5];
    sh2[0] = s15 * ux * uz;
    sh2[1] = s15 * ux * uy;
    sh2[2] = s5 * (uy*uy - 0.5f*(ux*ux + uz*uz));
    sh2[3] = s15 * uy * uz;
    sh2[4] = 0.5f * s15 * (uz*uz - ux*ux);
    float* orow = out + dst*OUTC + 16;
    #pragma unroll
    for (int u = 0; u < 16; ++u) atomicAdd(&orow[u], accS[u] * sc);
    #pragma unroll
    for (int u = 0; u < 4; ++u) {
        float v = accV[u] * sc;
        atomicAdd(&orow[16 + u*3 + 0], v * sh1x);
        atomicAdd(&orow[16 + u*3 + 1], v * sh1y);
        atomicAdd(&orow[16 + u*3 + 2], v * sh1z);
    }
    #pragma unroll
    for (int u = 0; u < 2; ++u) {
        float v = accT[u] * sc;
        #pragma unroll
        for (int mm = 0; mm < 5; ++mm)
            atomicAdd(&orow[28 + u*5 + mm], v * sh2[mm]);
    }
}

extern "C" void kernel_launch(void* const* d_in, const int* in_sizes, int n_in,
                              void* d_out, int out_size, void* d_ws, size_t ws_size,
                              hipStream_t stream) {
    const float* x   = (const float*)d_in[0];
    const float* pos = (const float*)d_in[1];
    const int*   ei  = (const int*)d_in[2];
    const float* We1 = (const float*)d_in[3];
    const float* We2 = (const float*)d_in[4];
    const float* Wt1 = (const float*)d_in[5];
    const float* Wt2 = (const float*)d_in[6];
    float* out = (float*)d_out;

    char* base = (char*)d_ws;
    size_t off = 0;
    unsigned short* tp = (unsigned short*)(base + off);
    off += (size_t)N_EDGES * TPW * 2;                    // fp16 rows, 21 MB
    float* T  = (float*)(base + off);       off += (size_t)TBLOCKS * TENT * 4;  // 2.1 MB
    float* znode = (float*)(base + off);    off += (size_t)N_NODES * 16 * 4;    // 2 MB
    float4* evec = (float4*)(base + off);   off += (size_t)N_EDGES * 16;        // 4 MB
    int* cursor_dst = (int*)(base + off);   off += (size_t)32768 * 4;
    int* cursor_bin = (int*)(base + off);   off += (size_t)32768 * 4;
    int* start_dst  = (int*)(base + off);   off += (size_t)32769 * 4;
    int* start_bin  = (int*)(base + off);   off += (size_t)32769 * 4;
    int* ebin       = (int*)(base + off);   off += (size_t)N_EDGES * 4;
    int4* binfo     = (int4*)(base + off);  off += (size_t)N_EDGES * 16;
    int2* elist2    = (int2*)(base + off);  off += (size_t)N_EDGES * 8;
    size_t need = off;

    if (ws_size >= need) {
        node_emb_kernel<<<N_NODES/256, 256, 0, stream>>>(x, We1, We2, out, znode,
                                                         cursor_dst, cursor_bin);
        prep_kernel<<<TBLOCKS + CBLK2, 256, 0, stream>>>(
            Wt1, Wt2, T, ei, pos, cursor_dst, cursor_bin, ebin, evec);
        scan2_kernel<<<2, 1024, 0, stream>>>(cursor_dst, start_dst,
                                             cursor_bin, start_bin);
        fill_bins_kernel<<<N_EDGES/256, 256, 0, stream>>>(ebin, ei, cursor_bin,
                                                          binfo);
        edge_table_binned<<<N_EDGES/256, 256, 0, stream>>>(evec, T, znode,
                                                           binfo, tp,
                                                           cursor_dst, elist2);
        gather_sorted_kernel<<<N_NODES/4, 256, 0, stream>>>(tp, start_dst,
                                                            elist2, out);
    } else {
        hipMemsetAsync(out, 0, (size_t)out_size * sizeof(float), stream);
        node_emb_fb_kernel<<<N_NODES/256, 256, 0, stream>>>(x, We1, We2, out);
        edge_kernel_atomic<<<N_EDGES/256, 256, 0, stream>>>(pos, ei, Wt1, Wt2, out);
    }
}